// Round 3
// baseline (1064.907 us; speedup 1.0000x reference)
//
#include <hip/hip_runtime.h>
#include <hip/hip_bf16.h>
#include <stdint.h>

#define DI __device__ __forceinline__

typedef __attribute__((ext_vector_type(8))) short short8;
typedef __attribute__((ext_vector_type(4))) float floatx4;

DI float bf2f(short u) {
  union { unsigned int i; float f; } v;
  v.i = ((unsigned int)(unsigned short)u) << 16;
  return v.f;
}
DI short f2bf(float f) {
  union { float f; unsigned int i; } v; v.f = f;
  unsigned int r = v.i + 0x7FFFu + ((v.i >> 16) & 1u);
  return (short)(r >> 16);
}

DI void gload16(const void* g, void* l) {
  __builtin_amdgcn_global_load_lds(
      (const __attribute__((address_space(1))) void*)g,
      (__attribute__((address_space(3))) void*)l,
      16, 0, 0);
}

// ---------------- weight conversion ----------------
__global__ __launch_bounds__(256) void k_cvt(const float* __restrict__ src,
                                             short* __restrict__ dst, int n) {
  int i = blockIdx.x * 256 + threadIdx.x;
  if (i < n) dst[i] = f2bf(src[i]);
}

// W2 [c*64+po][pi][3][3] -> W2R [((c*9+tap)*64+po)*64+pi]
__global__ __launch_bounds__(256) void k_w2r(const float* __restrict__ W2,
                                             short* __restrict__ W2R) {
  int idx = blockIdx.x * 256 + threadIdx.x;
  if (idx >= 32 * 9 * 64 * 64) return;
  int pi = idx & 63;
  int po = (idx >> 6) & 63;
  int ct = idx >> 12;  // c*9+tap
  int tap = ct % 9, c = ct / 9;
  W2R[idx] = f2bf(W2[((c * 64 + po) * 64 + pi) * 9 + tap]);
}

// x [b][d][n] f32 -> xT [b*49+n][d] bf16
__global__ __launch_bounds__(256) void k_xt(const float* __restrict__ x,
                                            short* __restrict__ xT) {
  __shared__ float tile[64 * 49];
  int b = blockIdx.x, dc = blockIdx.y;
  const float* xp = x + ((size_t)b * 2048 + dc * 64) * 49;
  for (int i = threadIdx.x; i < 64 * 49; i += 256) tile[i] = xp[i];
  __syncthreads();
  for (int i = threadIdx.x; i < 64 * 49; i += 256) {
    int n = i >> 6, dl = i & 63;
    xT[((size_t)(b * 49 + n)) * 2048 + dc * 64 + dl] = f2bf(tile[dl * 49 + n]);
  }
}

// ---------------- GEMM1: XcPad[b][81][e] = BN(xT @ W1^T) (interior cells) ---
// 1D grid 1568, XCD-swizzled, double-buffered prefetch.
__global__ __launch_bounds__(256) void k_gemm1(
    const short* __restrict__ xT, const short* __restrict__ W1b,
    const float* __restrict__ g1, const float* __restrict__ b1,
    short* __restrict__ XcPad) {
  __shared__ __attribute__((aligned(16))) short As[2][4096];
  __shared__ __attribute__((aligned(16))) short Bs[2][4096];
  const int tid = threadIdx.x;
  const int wave = tid >> 6, lane = tid & 63;
  // XCD swizzle: 1568 blocks = 8 XCDs x 196, mt-major chunks
  const int wg = blockIdx.x;
  const int swz = (wg & 7) * 196 + (wg >> 3);
  const int mt = swz >> 4, et = swz & 15;
  const int srow = tid >> 2, schunk = tid & 3;
  const short* asrc0 = xT + (size_t)(mt * 128 + srow) * 2048 + schunk * 8;
  const short* asrc1 = asrc0 + (size_t)64 * 2048;
  const short* bsrc0 = W1b + (size_t)(et * 128 + srow) * 2048 + schunk * 8;
  const short* bsrc1 = bsrc0 + (size_t)64 * 2048;
  const int wr = wave >> 1, wc = wave & 1;
  const int aoff = (wr * 64 + (lane & 15)) * 32 + (lane >> 4) * 8;
  const int boff = (wc * 64 + (lane & 15)) * 32 + (lane >> 4) * 8;
  floatx4 acc[4][4] = {};
  auto STAGE = [&](int buf, int kt) {
    const int ko = kt * 32;
    gload16(asrc0 + ko, &As[buf][wave * 512]);
    gload16(asrc1 + ko, &As[buf][2048 + wave * 512]);
    gload16(bsrc0 + ko, &Bs[buf][wave * 512]);
    gload16(bsrc1 + ko, &Bs[buf][2048 + wave * 512]);
  };
  auto COMPUTE = [&](int buf) {
    short8 a[4], b[4];
#pragma unroll
    for (int i = 0; i < 4; ++i) a[i] = *(const short8*)&As[buf][aoff + i * 512];
#pragma unroll
    for (int j = 0; j < 4; ++j) b[j] = *(const short8*)&Bs[buf][boff + j * 512];
#pragma unroll
    for (int i = 0; i < 4; ++i)
#pragma unroll
      for (int j = 0; j < 4; ++j)
        acc[i][j] = __builtin_amdgcn_mfma_f32_16x16x32_bf16(a[i], b[j], acc[i][j], 0, 0, 0);
  };
  STAGE(0, 0);
  __syncthreads();
#pragma unroll 1
  for (int kt = 0; kt < 62; kt += 2) {
    STAGE(1, kt + 1);
    COMPUTE(0);
    __syncthreads();
    STAGE(0, kt + 2);
    COMPUTE(1);
    __syncthreads();
  }
  STAGE(1, 63);
  COMPUTE(0);
  __syncthreads();
  COMPUTE(1);
  const float rs = rsqrtf(1.0f + 1e-5f);
  size_t abase[16];
#pragma unroll
  for (int i = 0; i < 4; ++i)
#pragma unroll
    for (int r = 0; r < 4; ++r) {
      int m = mt * 128 + wr * 64 + i * 16 + (lane >> 4) * 4 + r;
      int bb = m / 49, n = m % 49, h = n / 7, w = n % 7;
      abase[i * 4 + r] = ((size_t)bb * 81 + (h + 1) * 9 + (w + 1)) * 2048;
    }
#pragma unroll
  for (int j = 0; j < 4; ++j) {
    int e = et * 128 + wc * 64 + j * 16 + (lane & 15);
    float s = g1[e] * rs, bo = b1[e];
#pragma unroll
    for (int i = 0; i < 4; ++i)
#pragma unroll
      for (int r = 0; r < 4; ++r)
        XcPad[abase[i * 4 + r] + e] = f2bf(acc[i][j][r] * s + bo);
  }
}

// ---------------- grouped 3x3 conv via 9 accumulated taps ----------------
// 1D grid 3136, XCD-swizzled, double-buffered prefetch over 18 stages.
__global__ __launch_bounds__(256) void k_conv(
    const short* __restrict__ XcPad, const short* __restrict__ W2R,
    const float* __restrict__ g2, const float* __restrict__ b2,
    short* __restrict__ ZcT) {
  __shared__ __attribute__((aligned(16))) short As[2][4096];
  __shared__ __attribute__((aligned(16))) short Bs[2][2048];
  const int tid = threadIdx.x;
  const int wave = tid >> 6, lane = tid & 63;
  const int wg = blockIdx.x;
  const int swz = (wg & 7) * 392 + (wg >> 3);
  const int mt = swz >> 5, c = swz & 31;
  const int srow = tid >> 2, schunk = tid & 3;
  int m0 = mt * 128 + srow;
  int b0 = m0 / 49, n0 = m0 % 49, h0 = n0 / 7, w0 = n0 % 7;
  int m1 = m0 + 64;
  int b1v = m1 / 49, n1 = m1 % 49, h1 = n1 / 7, w1 = n1 % 7;
  const size_t base0 = ((size_t)b0 * 81 + (h0 + 1) * 9 + (w0 + 1)) * 2048;
  const size_t base1 = ((size_t)b1v * 81 + (h1 + 1) * 9 + (w1 + 1)) * 2048;
  const short* abase = XcPad + (size_t)c * 64 + schunk * 8;
  const short* wbase = W2R + (size_t)c * 9 * 4096 + srow * 64 + schunk * 8;
  const int wr = wave >> 1, wc = wave & 1;
  const int aoff = (wr * 64 + (lane & 15)) * 32 + (lane >> 4) * 8;
  const int boff = (wc * 32 + (lane & 15)) * 32 + (lane >> 4) * 8;
  floatx4 acc[4][2] = {};
  auto CSTAGE = [&](int buf, int s) {
    const int tap = s >> 1, kk = s & 1;
    // pad-relative tap offset: (dy-1)*9+(dx-1) rows of 2048
    const int toff = ((tap / 3 - 1) * 9 + (tap % 3 - 1)) * 2048;
    gload16(abase + base0 + toff + kk * 32, &As[buf][wave * 512]);
    gload16(abase + base1 + toff + kk * 32, &As[buf][2048 + wave * 512]);
    gload16(wbase + tap * 4096 + kk * 32, &Bs[buf][wave * 512]);
  };
  auto CCOMPUTE = [&](int buf) {
    short8 a[4], b[2];
#pragma unroll
    for (int i = 0; i < 4; ++i) a[i] = *(const short8*)&As[buf][aoff + i * 512];
#pragma unroll
    for (int j = 0; j < 2; ++j) b[j] = *(const short8*)&Bs[buf][boff + j * 512];
#pragma unroll
    for (int i = 0; i < 4; ++i)
#pragma unroll
      for (int j = 0; j < 2; ++j)
        acc[i][j] = __builtin_amdgcn_mfma_f32_16x16x32_bf16(a[i], b[j], acc[i][j], 0, 0, 0);
  };
  CSTAGE(0, 0);
  __syncthreads();
#pragma unroll 1
  for (int s = 0; s < 16; s += 2) {
    CSTAGE(1, s + 1);
    CCOMPUTE(0);
    __syncthreads();
    CSTAGE(0, s + 2);
    CCOMPUTE(1);
    __syncthreads();
  }
  CSTAGE(1, 17);
  CCOMPUTE(0);
  __syncthreads();
  CCOMPUTE(1);
  const float rs = rsqrtf(1.0f + 1e-5f);
#pragma unroll
  for (int j = 0; j < 2; ++j) {
    int e = c * 64 + wc * 32 + j * 16 + (lane & 15);
    float s = g2[e] * rs, bo = b2[e];
#pragma unroll
    for (int i = 0; i < 4; ++i)
#pragma unroll
      for (int r = 0; r < 4; ++r) {
        int m = mt * 128 + wr * 64 + i * 16 + (lane >> 4) * 4 + r;
        ZcT[(size_t)m * 2048 + e] = f2bf(acc[i][j][r] * s + bo);
      }
  }
}

// ---------------- fused pooled-mean + q + scores ----------------
__global__ __launch_bounds__(256) void k_scores(
    const short* __restrict__ ZcT, const float* __restrict__ Wq,
    const float* __restrict__ gq, const float* __restrict__ bq,
    const float* __restrict__ Wk, const float* __restrict__ gk,
    const float* __restrict__ bk, float* __restrict__ scores) {
  int b = blockIdx.x, t = threadIdx.x;
  __shared__ float pooled[2048];
  __shared__ float qv[128];
  const float rs = rsqrtf(1.0f + 1e-5f);
  for (int e = t; e < 2048; e += 256) {
    float s = 0.f;
    for (int n = 0; n < 49; ++n) s += bf2f(ZcT[((size_t)(b * 49 + n)) * 2048 + e]);
    pooled[e] = s * (1.0f / 49.0f);
  }
  __syncthreads();
  if (t < 128) {
    int c = t >> 2;
    float s = 0.f;
    for (int pi = 0; pi < 64; ++pi) s += Wq[t * 64 + pi] * pooled[c * 64 + pi];
    qv[t] = s * gq[t] * rs + bq[t];
  }
  __syncthreads();
  for (int idx = t; idx < 1568; idx += 256) {
    int c = idx / 49, n = idx % 49;
    const short8* z = (const short8*)&ZcT[((size_t)(b * 49 + n)) * 2048 + c * 64];
    float acc[4] = {0.f, 0.f, 0.f, 0.f};
#pragma unroll
    for (int p8 = 0; p8 < 8; ++p8) {
      short8 v = z[p8];
#pragma unroll
      for (int j = 0; j < 8; ++j) {
        float zv = bf2f(v[j]);
#pragma unroll
        for (int pq = 0; pq < 4; ++pq)
          acc[pq] += Wk[(c * 4 + pq) * 64 + p8 * 8 + j] * zv;
      }
    }
    float sc = 0.f;
#pragma unroll
    for (int pq = 0; pq < 4; ++pq) {
      float kv = acc[pq] * gk[c * 4 + pq] * rs + bk[c * 4 + pq];
      sc += qv[c * 4 + pq] * kv;
    }
    scores[b * 1568 + idx] = sc;
  }
}

// ---------------- softmax over BATCH dim (torch Softmax2d quirk) ----------
__global__ __launch_bounds__(256) void k_softmax(const float* __restrict__ scores,
                                                 float* __restrict__ Msm,
                                                 unsigned int* __restrict__ maxM) {
  int cn = blockIdx.x, t = threadIdx.x;  // t = b
  float v = scores[t * 1568 + cn];
  __shared__ float red[4], red2[4];
  float m = v;
#pragma unroll
  for (int o = 1; o < 64; o <<= 1) m = fmaxf(m, __shfl_xor(m, o));
  if ((t & 63) == 0) red[t >> 6] = m;
  __syncthreads();
  m = fmaxf(fmaxf(red[0], red[1]), fmaxf(red[2], red[3]));
  float e = expf(v - m);
  float s = e;
#pragma unroll
  for (int o = 1; o < 64; o <<= 1) s += __shfl_xor(s, o);
  if ((t & 63) == 0) red2[t >> 6] = s;
  __syncthreads();
  s = red2[0] + red2[1] + red2[2] + red2[3];
  Msm[t * 1568 + cn] = e / s;
  if (t == 0) atomicMax(maxM, __float_as_uint(1.0f / s));  // column max of M == 1/sum
}

// ---------------- per-batch attention tail: zout->hc->A->hc_->va/vb -------
__global__ __launch_bounds__(256) void k_tail(
    const short* __restrict__ ZcT, const float* __restrict__ Msm,
    const float* __restrict__ Wout, const float* __restrict__ gout,
    const float* __restrict__ bout, const float* __restrict__ Wcr,
    const float* __restrict__ gcr, const float* __restrict__ bcr,
    const float* __restrict__ gcr1, const float* __restrict__ bcr1,
    const float* __restrict__ Wa, const float* __restrict__ Wb,
    float* __restrict__ va, float* __restrict__ vb) {
  int b = blockIdx.x, t = threadIdx.x;
  __shared__ float Mrow[1568];
  __shared__ float zout[2048];
  __shared__ float hcl[128];
  __shared__ float tb[1024];
  __shared__ float hcp[128];
  const float rs = rsqrtf(1.0f + 1e-5f);
  for (int i = t; i < 1568; i += 256) Mrow[i] = Msm[b * 1568 + i];
  __syncthreads();
  for (int e = t; e < 2048; e += 256) {
    int c = e >> 6;
    float s = 0.f;
    for (int n = 0; n < 49; ++n)
      s += bf2f(ZcT[((size_t)(b * 49 + n)) * 2048 + e]) * Mrow[c * 49 + n];
    zout[e] = s;
  }
  __syncthreads();
  if (t < 128) {
    int c = t >> 2;
    float s = 0.f;
    for (int p = 0; p < 64; ++p) s += Wout[t * 64 + p] * zout[c * 64 + p];
    hcl[t] = s * gout[t] * rs + bout[t];
  }
  __syncthreads();
  for (int i = t; i < 1024; i += 256) {
    int c = i >> 5;
    float s = 0.f;
#pragma unroll
    for (int k = 0; k < 4; ++k) s += Wcr[i * 4 + k] * hcl[c * 4 + k];
    tb[i] = tanhf(s * gcr[i] * rs + bcr[i]);
  }
  __syncthreads();
  if (t < 128) {
    int i = t >> 2, pq = t & 3;
    float s = hcl[t];
    for (int j = 0; j < 32; ++j) s += tb[j * 32 + i] * hcl[j * 4 + pq];
    hcp[t] = fmaxf(s * gcr1[t] * rs + bcr1[t], 0.0f);
  }
  __syncthreads();
  for (int e = t; e < 2048; e += 256) {
    int c = e >> 6;
    float sa = 0.f, sb = 0.f;
#pragma unroll
    for (int pq = 0; pq < 4; ++pq) {
      float h = hcp[c * 4 + pq];
      sa += Wa[e * 4 + pq] * h;
      sb += Wb[e * 4 + pq] * h;
    }
    va[b * 2048 + e] = sa;
    vb[b * 2048 + e] = sb;
  }
}

// ---------------- cm = Zc * relu(Zc*alpha + beta), vectorized ----------------
__global__ __launch_bounds__(256) void k_cm(
    const short* __restrict__ ZcT, const float* __restrict__ Msm,
    const unsigned int* __restrict__ maxM, const float* __restrict__ va,
    const float* __restrict__ vb, const float* __restrict__ ba,
    const float* __restrict__ bb, short* __restrict__ cm) {
  int m = blockIdx.x;
  int b = m / 49, n = m % 49;
  __shared__ float Minv[32];
  if (threadIdx.x < 32) {
    float mx = __uint_as_float(*maxM);
    Minv[threadIdx.x] = Msm[b * 1568 + threadIdx.x * 49 + n] / mx;
  }
  __syncthreads();
  const int e0 = threadIdx.x * 8;
  short8 z8 = *(const short8*)&ZcT[(size_t)m * 2048 + e0];
  const float mi = Minv[e0 >> 6];
  short8 o;
#pragma unroll
  for (int j = 0; j < 8; ++j) {
    float zc = bf2f(z8[j]);
    float al = va[b * 2048 + e0 + j] * mi + ba[e0 + j];
    float bt = vb[b * 2048 + e0 + j] * mi + bb[e0 + j];
    float xc = fmaxf(zc * al + bt, 0.0f);
    o[j] = f2bf(zc * xc);
  }
  *(short8*)&cm[(size_t)m * 2048 + e0] = o;
}

// ---------------- GEMM2: OUT[b][d][n] = BN(W3 @ cm^T) + x ----------------
__global__ __launch_bounds__(256) void k_gemm2(
    const short* __restrict__ W3b, const short* __restrict__ cm,
    const float* __restrict__ g3, const float* __restrict__ b3,
    const float* __restrict__ x, float* __restrict__ out) {
  __shared__ __attribute__((aligned(16))) short As[2][4096];
  __shared__ __attribute__((aligned(16))) short Bs[2][4096];
  const int tid = threadIdx.x;
  const int wave = tid >> 6, lane = tid & 63;
  const int wg = blockIdx.x;
  const int swz = (wg & 7) * 196 + (wg >> 3);
  const int mt = swz >> 4, dt = swz & 15;
  const int srow = tid >> 2, schunk = tid & 3;
  const short* asrc0 = W3b + (size_t)(dt * 128 + srow) * 2048 + schunk * 8;
  const short* asrc1 = asrc0 + (size_t)64 * 2048;
  const short* bsrc0 = cm + (size_t)(mt * 128 + srow) * 2048 + schunk * 8;
  const short* bsrc1 = bsrc0 + (size_t)64 * 2048;
  const int wr = wave >> 1, wc = wave & 1;
  const int aoff = (wr * 64 + (lane & 15)) * 32 + (lane >> 4) * 8;
  const int boff = (wc * 64 + (lane & 15)) * 32 + (lane >> 4) * 8;
  floatx4 acc[4][4] = {};
  auto STAGE = [&](int buf, int kt) {
    const int ko = kt * 32;
    gload16(asrc0 + ko, &As[buf][wave * 512]);
    gload16(asrc1 + ko, &As[buf][2048 + wave * 512]);
    gload16(bsrc0 + ko, &Bs[buf][wave * 512]);
    gload16(bsrc1 + ko, &Bs[buf][2048 + wave * 512]);
  };
  auto COMPUTE = [&](int buf) {
    short8 a[4], b[4];
#pragma unroll
    for (int i = 0; i < 4; ++i) a[i] = *(const short8*)&As[buf][aoff + i * 512];
#pragma unroll
    for (int j = 0; j < 4; ++j) b[j] = *(const short8*)&Bs[buf][boff + j * 512];
#pragma unroll
    for (int i = 0; i < 4; ++i)
#pragma unroll
      for (int j = 0; j < 4; ++j)
        acc[i][j] = __builtin_amdgcn_mfma_f32_16x16x32_bf16(a[i], b[j], acc[i][j], 0, 0, 0);
  };
  STAGE(0, 0);
  __syncthreads();
#pragma unroll 1
  for (int kt = 0; kt < 62; kt += 2) {
    STAGE(1, kt + 1);
    COMPUTE(0);
    __syncthreads();
    STAGE(0, kt + 2);
    COMPUTE(1);
    __syncthreads();
  }
  STAGE(1, 63);
  COMPUTE(0);
  __syncthreads();
  COMPUTE(1);
  const float rs = rsqrtf(1.0f + 1e-5f);
  size_t cbb[4];
#pragma unroll
  for (int j = 0; j < 4; ++j) {
    int m = mt * 128 + wc * 64 + j * 16 + (lane & 15);
    int bb = m / 49, n = m % 49;
    cbb[j] = (size_t)bb * (2048 * 49) + n;
  }
#pragma unroll
  for (int i = 0; i < 4; ++i)
#pragma unroll
    for (int r = 0; r < 4; ++r) {
      int d = dt * 128 + wr * 64 + i * 16 + (lane >> 4) * 4 + r;
      float s = g3[d] * rs, bo = b3[d];
      size_t dterm = (size_t)d * 49;
#pragma unroll
      for (int j = 0; j < 4; ++j) {
        size_t adr = cbb[j] + dterm;
        out[adr] = acc[i][j][r] * s + bo + x[adr];
      }
    }
}

// ---------------- launch ----------------
extern "C" void kernel_launch(void* const* d_in, const int* in_sizes, int n_in,
                              void* d_out, int out_size, void* d_ws, size_t ws_size,
                              hipStream_t stream) {
  (void)in_sizes; (void)n_in; (void)out_size; (void)ws_size;
  const float* x    = (const float*)d_in[0];
  const float* W1   = (const float*)d_in[1];
  const float* g1   = (const float*)d_in[2];
  const float* b1   = (const float*)d_in[3];
  const float* W2   = (const float*)d_in[4];
  const float* g2   = (const float*)d_in[5];
  const float* b2   = (const float*)d_in[6];
  const float* Wq   = (const float*)d_in[7];
  const float* gq   = (const float*)d_in[8];
  const float* bq   = (const float*)d_in[9];
  const float* Wk   = (const float*)d_in[10];
  const float* gk   = (const float*)d_in[11];
  const float* bk   = (const float*)d_in[12];
  const float* Wout = (const float*)d_in[13];
  const float* gout = (const float*)d_in[14];
  const float* bout = (const float*)d_in[15];
  const float* Wcr  = (const float*)d_in[16];
  const float* gcr  = (const float*)d_in[17];
  const float* bcr  = (const float*)d_in[18];
  const float* gcr1 = (const float*)d_in[19];
  const float* bcr1 = (const float*)d_in[20];
  const float* Wa   = (const float*)d_in[21];
  const float* ba   = (const float*)d_in[22];
  const float* Wb   = (const float*)d_in[23];
  const float* bb   = (const float*)d_in[24];
  const float* W3   = (const float*)d_in[25];
  const float* g3   = (const float*)d_in[26];
  const float* b3   = (const float*)d_in[27];
  float* out = (float*)d_out;

  char* ws = (char*)d_ws;
  short* XcPad  = (short*)(ws + 0);           // 256*81*2048*2 = 84934656
  short* xT     = (short*)(ws + 84934656);    // 12544*2048*2 = 51380224 (reused as cm)
  short* ZcT    = (short*)(ws + 136314880);   // 51380224
  short* W1b    = (short*)(ws + 187695104);   // 8388608
  short* W3b    = (short*)(ws + 196083712);   // 8388608
  short* W2R    = (short*)(ws + 204472320);   // 2359296
  float* qb     = (float*)(ws + 208928768);   // 131072
  float* scores = (float*)(ws + 209059840);   // 1605632
  float* Msm    = (float*)(ws + 210665472);   // 1605632
  float* va     = (float*)(ws + 212271104);   // 2097152
  float* vb     = (float*)(ws + 214368256);   // 2097152
  unsigned int* maxM = (unsigned int*)(ws + 216465408);
  short* cm = xT;
  (void)qb;

  hipMemsetAsync(XcPad, 0, 84934656, stream);
  hipMemsetAsync(maxM, 0, 4, stream);

  k_cvt<<<16384, 256, 0, stream>>>(W1, W1b, 4194304);
  k_cvt<<<16384, 256, 0, stream>>>(W3, W3b, 4194304);
  k_w2r<<<4608, 256, 0, stream>>>(W2, W2R);
  k_xt<<<dim3(256, 32), 256, 0, stream>>>(x, xT);
  k_gemm1<<<1568, 256, 0, stream>>>(xT, W1b, g1, b1, XcPad);
  k_conv<<<3136, 256, 0, stream>>>(XcPad, W2R, g2, b2, ZcT);
  k_scores<<<256, 256, 0, stream>>>(ZcT, Wq, gq, bq, Wk, gk, bk, scores);
  k_softmax<<<1568, 256, 0, stream>>>(scores, Msm, maxM);
  k_tail<<<256, 256, 0, stream>>>(ZcT, Msm, Wout, gout, bout, Wcr, gcr, bcr,
                                  gcr1, bcr1, Wa, Wb, va, vb);
  k_cm<<<12544, 256, 0, stream>>>(ZcT, Msm, maxM, va, vb, ba, bb, cm);
  k_gemm2<<<1568, 256, 0, stream>>>(W3b, cm, g3, b3, x, out);
}

// Round 5
// 903.161 us; speedup vs baseline: 1.1791x; 1.1791x over previous
//
#include <hip/hip_runtime.h>
#include <hip/hip_bf16.h>
#include <stdint.h>

#define DI __device__ __forceinline__

typedef __attribute__((ext_vector_type(8))) short short8;
typedef __attribute__((ext_vector_type(4))) float floatx4;

DI float bf2f(short u) {
  union { unsigned int i; float f; } v;
  v.i = ((unsigned int)(unsigned short)u) << 16;
  return v.f;
}
DI short f2bf(float f) {
  union { float f; unsigned int i; } v; v.f = f;
  unsigned int r = v.i + 0x7FFFu + ((v.i >> 16) & 1u);
  return (short)(r >> 16);
}

DI void gload16(const void* g, void* l) {
  __builtin_amdgcn_global_load_lds(
      (const __attribute__((address_space(1))) void*)g,
      (__attribute__((address_space(3))) void*)l,
      16, 0, 0);
}

// ---------------- weight conversion ----------------
__global__ __launch_bounds__(256) void k_cvt(const float* __restrict__ src,
                                             short* __restrict__ dst, int n) {
  int i = blockIdx.x * 256 + threadIdx.x;
  if (i < n) dst[i] = f2bf(src[i]);
}

// W2 [c*64+po][pi][3][3] -> W2R [((c*9+tap)*64+po)*64+pi]
__global__ __launch_bounds__(256) void k_w2r(const float* __restrict__ W2,
                                             short* __restrict__ W2R) {
  int idx = blockIdx.x * 256 + threadIdx.x;
  if (idx >= 32 * 9 * 64 * 64) return;
  int pi = idx & 63;
  int po = (idx >> 6) & 63;
  int ct = idx >> 12;  // c*9+tap
  int tap = ct % 9, c = ct / 9;
  W2R[idx] = f2bf(W2[((c * 64 + po) * 64 + pi) * 9 + tap]);
}

// x [b][d][n] f32 -> xT [b*49+n][d] bf16
__global__ __launch_bounds__(256) void k_xt(const float* __restrict__ x,
                                            short* __restrict__ xT) {
  __shared__ float tile[64 * 49];
  int b = blockIdx.x, dc = blockIdx.y;
  const float* xp = x + ((size_t)b * 2048 + dc * 64) * 49;
  for (int i = threadIdx.x; i < 64 * 49; i += 256) tile[i] = xp[i];
  __syncthreads();
  for (int i = threadIdx.x; i < 64 * 49; i += 256) {
    int n = i >> 6, dl = i & 63;
    xT[((size_t)(b * 49 + n)) * 2048 + dc * 64 + dl] = f2bf(tile[dl * 49 + n]);
  }
}

// ---------------- GEMM1: XcPad[b][81][e] = BN(xT @ W1^T) ----------------
// 512 thr / 8 waves, per-wave 64x32 out (acc[4][2]=32 AGPR), 2-barrier K-loop.
__global__ __launch_bounds__(512, 4) void k_gemm1(
    const short* __restrict__ xT, const short* __restrict__ W1b,
    const float* __restrict__ g1, const float* __restrict__ b1,
    short* __restrict__ XcPad) {
  __shared__ __attribute__((aligned(16))) short As[4096];
  __shared__ __attribute__((aligned(16))) short Bs[4096];
  const int tid = threadIdx.x;
  const int wave = tid >> 6, lane = tid & 63;
  const int wg = blockIdx.x;
  const int swz = (wg & 7) * 196 + (wg >> 3);
  const int mt = swz >> 4, et = swz & 15;
  const int srow = tid >> 2, schunk = tid & 3;
  const short* asrc = xT + (size_t)(mt * 128 + srow) * 2048 + schunk * 8;
  const short* bsrc = W1b + (size_t)(et * 128 + srow) * 2048 + schunk * 8;
  short* alds = &As[wave * 512];
  short* blds = &Bs[wave * 512];
  const int wr = wave >> 2, wc = wave & 3;  // 2 x 4 wave grid
  const int aoff = (wr * 64 + (lane & 15)) * 32 + (lane >> 4) * 8;
  const int boff = (wc * 32 + (lane & 15)) * 32 + (lane >> 4) * 8;
  floatx4 acc[4][2] = {};
#pragma unroll 1
  for (int kt = 0; kt < 64; ++kt) {
    const int ko = kt * 32;
    gload16(asrc + ko, alds);
    gload16(bsrc + ko, blds);
    __syncthreads();
    short8 a[4], b[2];
#pragma unroll
    for (int i = 0; i < 4; ++i) a[i] = *(const short8*)&As[aoff + i * 512];
#pragma unroll
    for (int j = 0; j < 2; ++j) b[j] = *(const short8*)&Bs[boff + j * 512];
#pragma unroll
    for (int i = 0; i < 4; ++i)
#pragma unroll
      for (int j = 0; j < 2; ++j)
        acc[i][j] = __builtin_amdgcn_mfma_f32_16x16x32_bf16(a[i], b[j], acc[i][j], 0, 0, 0);
    __syncthreads();
  }
  const float rs = rsqrtf(1.0f + 1e-5f);
  size_t abase[16];
#pragma unroll
  for (int i = 0; i < 4; ++i)
#pragma unroll
    for (int r = 0; r < 4; ++r) {
      int m = mt * 128 + wr * 64 + i * 16 + (lane >> 4) * 4 + r;
      int bb = m / 49, n = m % 49, h = n / 7, w = n % 7;
      abase[i * 4 + r] = ((size_t)bb * 81 + (h + 1) * 9 + (w + 1)) * 2048;
    }
#pragma unroll
  for (int j = 0; j < 2; ++j) {
    int e = et * 128 + wc * 32 + j * 16 + (lane & 15);
    float s = g1[e] * rs, bo = b1[e];
#pragma unroll
    for (int i = 0; i < 4; ++i)
#pragma unroll
      for (int r = 0; r < 4; ++r)
        XcPad[abase[i * 4 + r] + e] = f2bf(acc[i][j][r] * s + bo);
  }
}

// ---------------- grouped 3x3 conv via 9 accumulated taps ----------------
// 512 thr / 8 waves, per-wave 32x32 out (acc[2][2]=16 AGPR), 2-barrier loop.
__global__ __launch_bounds__(512, 4) void k_conv(
    const short* __restrict__ XcPad, const short* __restrict__ W2R,
    const float* __restrict__ g2, const float* __restrict__ b2,
    short* __restrict__ ZcT) {
  __shared__ __attribute__((aligned(16))) short As[4096];
  __shared__ __attribute__((aligned(16))) short Bs[2048];
  const int tid = threadIdx.x;
  const int wave = tid >> 6, lane = tid & 63;
  const int wg = blockIdx.x;
  const int swz = (wg & 7) * 392 + (wg >> 3);
  const int mt = swz >> 5, c = swz & 31;
  const int srow = tid >> 2, schunk = tid & 3;
  int m0 = mt * 128 + srow;
  int b0 = m0 / 49, n0 = m0 % 49, h0 = n0 / 7, w0 = n0 % 7;
  const short* abase = XcPad + (size_t)c * 64 + schunk * 8;
  const short* wbase = W2R + (size_t)c * 9 * 4096 + srow * 64 + schunk * 8;
  short* alds = &As[wave * 512];
  short* blds = &Bs[wave * 512];
  const int wr = wave >> 1, wc = wave & 1;  // 4 x 2 wave grid
  const int aoff = (wr * 32 + (lane & 15)) * 32 + (lane >> 4) * 8;
  const int boff = (wc * 32 + (lane & 15)) * 32 + (lane >> 4) * 8;
  floatx4 acc[2][2] = {};
#pragma unroll 1
  for (int tap = 0; tap < 9; ++tap) {
    const int dy = tap / 3, dx = tap % 3;
    const size_t r0 = ((size_t)b0 * 81 + (h0 + dy) * 9 + (w0 + dx)) * 2048;
#pragma unroll
    for (int kk = 0; kk < 2; ++kk) {
      gload16(abase + r0 + kk * 32, alds);
      if (wave < 4) gload16(wbase + tap * 4096 + kk * 32, blds);
      __syncthreads();
      short8 a[2], b[2];
#pragma unroll
      for (int i = 0; i < 2; ++i) a[i] = *(const short8*)&As[aoff + i * 512];
#pragma unroll
      for (int j = 0; j < 2; ++j) b[j] = *(const short8*)&Bs[boff + j * 512];
#pragma unroll
      for (int i = 0; i < 2; ++i)
#pragma unroll
        for (int j = 0; j < 2; ++j)
          acc[i][j] = __builtin_amdgcn_mfma_f32_16x16x32_bf16(a[i], b[j], acc[i][j], 0, 0, 0);
      __syncthreads();
    }
  }
  const float rs = rsqrtf(1.0f + 1e-5f);
#pragma unroll
  for (int j = 0; j < 2; ++j) {
    int e = c * 64 + wc * 32 + j * 16 + (lane & 15);
    float s = g2[e] * rs, bo = b2[e];
#pragma unroll
    for (int i = 0; i < 2; ++i)
#pragma unroll
      for (int r = 0; r < 4; ++r) {
        int m = mt * 128 + wr * 32 + i * 16 + (lane >> 4) * 4 + r;
        ZcT[(size_t)m * 2048 + e] = f2bf(acc[i][j][r] * s + bo);
      }
  }
}

// ---------------- fused pooled-mean + q + scores ----------------
__global__ __launch_bounds__(256) void k_scores(
    const short* __restrict__ ZcT, const float* __restrict__ Wq,
    const float* __restrict__ gq, const float* __restrict__ bq,
    const float* __restrict__ Wk, const float* __restrict__ gk,
    const float* __restrict__ bk, float* __restrict__ scores) {
  int b = blockIdx.x, t = threadIdx.x;
  __shared__ float pooled[2048];
  __shared__ float qv[128];
  const float rs = rsqrtf(1.0f + 1e-5f);
  for (int e = t; e < 2048; e += 256) {
    float s = 0.f;
    for (int n = 0; n < 49; ++n) s += bf2f(ZcT[((size_t)(b * 49 + n)) * 2048 + e]);
    pooled[e] = s * (1.0f / 49.0f);
  }
  __syncthreads();
  if (t < 128) {
    int c = t >> 2;
    float s = 0.f;
    for (int pi = 0; pi < 64; ++pi) s += Wq[t * 64 + pi] * pooled[c * 64 + pi];
    qv[t] = s * gq[t] * rs + bq[t];
  }
  __syncthreads();
  for (int idx = t; idx < 1568; idx += 256) {
    int c = idx / 49, n = idx % 49;
    const short8* z = (const short8*)&ZcT[((size_t)(b * 49 + n)) * 2048 + c * 64];
    float acc[4] = {0.f, 0.f, 0.f, 0.f};
#pragma unroll
    for (int p8 = 0; p8 < 8; ++p8) {
      short8 v = z[p8];
#pragma unroll
      for (int j = 0; j < 8; ++j) {
        float zv = bf2f(v[j]);
#pragma unroll
        for (int pq = 0; pq < 4; ++pq)
          acc[pq] += Wk[(c * 4 + pq) * 64 + p8 * 8 + j] * zv;
      }
    }
    float sc = 0.f;
#pragma unroll
    for (int pq = 0; pq < 4; ++pq) {
      float kv = acc[pq] * gk[c * 4 + pq] * rs + bk[c * 4 + pq];
      sc += qv[c * 4 + pq] * kv;
    }
    scores[b * 1568 + idx] = sc;
  }
}

// ---------------- softmax over BATCH dim (torch Softmax2d quirk) ----------
__global__ __launch_bounds__(256) void k_softmax(const float* __restrict__ scores,
                                                 float* __restrict__ Msm,
                                                 unsigned int* __restrict__ maxM) {
  int cn = blockIdx.x, t = threadIdx.x;  // t = b
  float v = scores[t * 1568 + cn];
  __shared__ float red[4], red2[4];
  float m = v;
#pragma unroll
  for (int o = 1; o < 64; o <<= 1) m = fmaxf(m, __shfl_xor(m, o));
  if ((t & 63) == 0) red[t >> 6] = m;
  __syncthreads();
  m = fmaxf(fmaxf(red[0], red[1]), fmaxf(red[2], red[3]));
  float e = expf(v - m);
  float s = e;
#pragma unroll
  for (int o = 1; o < 64; o <<= 1) s += __shfl_xor(s, o);
  if ((t & 63) == 0) red2[t >> 6] = s;
  __syncthreads();
  s = red2[0] + red2[1] + red2[2] + red2[3];
  Msm[t * 1568 + cn] = e / s;
  if (t == 0) atomicMax(maxM, __float_as_uint(1.0f / s));  // column max of M == 1/sum
}

// ---------------- per-batch attention tail: zout->hc->A->hc_->va/vb -------
__global__ __launch_bounds__(256) void k_tail(
    const short* __restrict__ ZcT, const float* __restrict__ Msm,
    const float* __restrict__ Wout, const float* __restrict__ gout,
    const float* __restrict__ bout, const float* __restrict__ Wcr,
    const float* __restrict__ gcr, const float* __restrict__ bcr,
    const float* __restrict__ gcr1, const float* __restrict__ bcr1,
    const float* __restrict__ Wa, const float* __restrict__ Wb,
    float* __restrict__ va, float* __restrict__ vb) {
  int b = blockIdx.x, t = threadIdx.x;
  __shared__ float Mrow[1568];
  __shared__ float zout[2048];
  __shared__ float hcl[128];
  __shared__ float tb[1024];
  __shared__ float hcp[128];
  const float rs = rsqrtf(1.0f + 1e-5f);
  for (int i = t; i < 1568; i += 256) Mrow[i] = Msm[b * 1568 + i];
  __syncthreads();
  for (int e = t; e < 2048; e += 256) {
    int c = e >> 6;
    float s = 0.f;
    for (int n = 0; n < 49; ++n)
      s += bf2f(ZcT[((size_t)(b * 49 + n)) * 2048 + e]) * Mrow[c * 49 + n];
    zout[e] = s;
  }
  __syncthreads();
  if (t < 128) {
    int c = t >> 2;
    float s = 0.f;
    for (int p = 0; p < 64; ++p) s += Wout[t * 64 + p] * zout[c * 64 + p];
    hcl[t] = s * gout[t] * rs + bout[t];
  }
  __syncthreads();
  for (int i = t; i < 1024; i += 256) {
    int c = i >> 5;
    float s = 0.f;
#pragma unroll
    for (int k = 0; k < 4; ++k) s += Wcr[i * 4 + k] * hcl[c * 4 + k];
    tb[i] = tanhf(s * gcr[i] * rs + bcr[i]);
  }
  __syncthreads();
  if (t < 128) {
    int i = t >> 2, pq = t & 3;
    float s = hcl[t];
    for (int j = 0; j < 32; ++j) s += tb[j * 32 + i] * hcl[j * 4 + pq];
    hcp[t] = fmaxf(s * gcr1[t] * rs + bcr1[t], 0.0f);
  }
  __syncthreads();
  for (int e = t; e < 2048; e += 256) {
    int c = e >> 6;
    float sa = 0.f, sb = 0.f;
#pragma unroll
    for (int pq = 0; pq < 4; ++pq) {
      float h = hcp[c * 4 + pq];
      sa += Wa[e * 4 + pq] * h;
      sb += Wb[e * 4 + pq] * h;
    }
    va[b * 2048 + e] = sa;
    vb[b * 2048 + e] = sb;
  }
}

// ---------------- cm = Zc * relu(Zc*alpha + beta), vectorized ----------------
__global__ __launch_bounds__(256) void k_cm(
    const short* __restrict__ ZcT, const float* __restrict__ Msm,
    const unsigned int* __restrict__ maxM, const float* __restrict__ va,
    const float* __restrict__ vb, const float* __restrict__ ba,
    const float* __restrict__ bb, short* __restrict__ cm) {
  int m = blockIdx.x;
  int b = m / 49, n = m % 49;
  __shared__ float Minv[32];
  if (threadIdx.x < 32) {
    float mx = __uint_as_float(*maxM);
    Minv[threadIdx.x] = Msm[b * 1568 + threadIdx.x * 49 + n] / mx;
  }
  __syncthreads();
  const int e0 = threadIdx.x * 8;
  short8 z8 = *(const short8*)&ZcT[(size_t)m * 2048 + e0];
  const float mi = Minv[e0 >> 6];
  short8 o;
#pragma unroll
  for (int j = 0; j < 8; ++j) {
    float zc = bf2f(z8[j]);
    float al = va[b * 2048 + e0 + j] * mi + ba[e0 + j];
    float bt = vb[b * 2048 + e0 + j] * mi + bb[e0 + j];
    float xc = fmaxf(zc * al + bt, 0.0f);
    o[j] = f2bf(zc * xc);
  }
  *(short8*)&cm[(size_t)m * 2048 + e0] = o;
}

// ---------------- GEMM2: OUT[b][d][n] = BN(W3 @ cm^T) + x ----------------
// 512 thr / 8 waves, per-wave 64(d) x 32(m) out (acc[4][2]), 2-barrier loop.
__global__ __launch_bounds__(512, 4) void k_gemm2(
    const short* __restrict__ W3b, const short* __restrict__ cm,
    const float* __restrict__ g3, const float* __restrict__ b3,
    const float* __restrict__ x, float* __restrict__ out) {
  __shared__ __attribute__((aligned(16))) short As[4096];
  __shared__ __attribute__((aligned(16))) short Bs[4096];
  const int tid = threadIdx.x;
  const int wave = tid >> 6, lane = tid & 63;
  const int wg = blockIdx.x;
  const int swz = (wg & 7) * 196 + (wg >> 3);
  const int mt = swz >> 4, dt = swz & 15;
  const int srow = tid >> 2, schunk = tid & 3;
  const short* asrc = W3b + (size_t)(dt * 128 + srow) * 2048 + schunk * 8;
  const short* bsrc = cm + (size_t)(mt * 128 + srow) * 2048 + schunk * 8;
  short* alds = &As[wave * 512];
  short* blds = &Bs[wave * 512];
  const int wr = wave >> 2, wc = wave & 3;  // 2(d) x 4(m) wave grid
  const int aoff = (wr * 64 + (lane & 15)) * 32 + (lane >> 4) * 8;
  const int boff = (wc * 32 + (lane & 15)) * 32 + (lane >> 4) * 8;
  floatx4 acc[4][2] = {};
#pragma unroll 1
  for (int kt = 0; kt < 64; ++kt) {
    const int ko = kt * 32;
    gload16(asrc + ko, alds);
    gload16(bsrc + ko, blds);
    __syncthreads();
    short8 a[4], b[2];
#pragma unroll
    for (int i = 0; i < 4; ++i) a[i] = *(const short8*)&As[aoff + i * 512];
#pragma unroll
    for (int j = 0; j < 2; ++j) b[j] = *(const short8*)&Bs[boff + j * 512];
#pragma unroll
    for (int i = 0; i < 4; ++i)
#pragma unroll
      for (int j = 0; j < 2; ++j)
        acc[i][j] = __builtin_amdgcn_mfma_f32_16x16x32_bf16(a[i], b[j], acc[i][j], 0, 0, 0);
    __syncthreads();
  }
  const float rs = rsqrtf(1.0f + 1e-5f);
  size_t cbb[2];
#pragma unroll
  for (int j = 0; j < 2; ++j) {
    int m = mt * 128 + wc * 32 + j * 16 + (lane & 15);
    int bb = m / 49, n = m % 49;
    cbb[j] = (size_t)bb * (2048 * 49) + n;
  }
#pragma unroll
  for (int i = 0; i < 4; ++i)
#pragma unroll
    for (int r = 0; r < 4; ++r) {
      int d = dt * 128 + wr * 64 + i * 16 + (lane >> 4) * 4 + r;
      float s = g3[d] * rs, bo = b3[d];
      size_t dterm = (size_t)d * 49;
#pragma unroll
      for (int j = 0; j < 2; ++j) {
        size_t adr = cbb[j] + dterm;
        out[adr] = acc[i][j][r] * s + bo + x[adr];
      }
    }
}

// ---------------- launch ----------------
extern "C" void kernel_launch(void* const* d_in, const int* in_sizes, int n_in,
                              void* d_out, int out_size, void* d_ws, size_t ws_size,
                              hipStream_t stream) {
  (void)in_sizes; (void)n_in; (void)out_size; (void)ws_size;
  const float* x    = (const float*)d_in[0];
  const float* W1   = (const float*)d_in[1];
  const float* g1   = (const float*)d_in[2];
  const float* b1   = (const float*)d_in[3];
  const float* W2   = (const float*)d_in[4];
  const float* g2   = (const float*)d_in[5];
  const float* b2   = (const float*)d_in[6];
  const float* Wq   = (const float*)d_in[7];
  const float* gq   = (const float*)d_in[8];
  const float* bq   = (const float*)d_in[9];
  const float* Wk   = (const float*)d_in[10];
  const float* gk   = (const float*)d_in[11];
  const float* bk   = (const float*)d_in[12];
  const float* Wout = (const float*)d_in[13];
  const float* gout = (const float*)d_in[14];
  const float* bout = (const float*)d_in[15];
  const float* Wcr  = (const float*)d_in[16];
  const float* gcr  = (const float*)d_in[17];
  const float* bcr  = (const float*)d_in[18];
  const float* gcr1 = (const float*)d_in[19];
  const float* bcr1 = (const float*)d_in[20];
  const float* Wa   = (const float*)d_in[21];
  const float* ba   = (const float*)d_in[22];
  const float* Wb   = (const float*)d_in[23];
  const float* bb   = (const float*)d_in[24];
  const float* W3   = (const float*)d_in[25];
  const float* g3   = (const float*)d_in[26];
  const float* b3   = (const float*)d_in[27];
  float* out = (float*)d_out;

  char* ws = (char*)d_ws;
  short* XcPad  = (short*)(ws + 0);           // 256*81*2048*2 = 84934656
  short* xT     = (short*)(ws + 84934656);    // 12544*2048*2 = 51380224 (reused as cm)
  short* ZcT    = (short*)(ws + 136314880);   // 51380224
  short* W1b    = (short*)(ws + 187695104);   // 8388608
  short* W3b    = (short*)(ws + 196083712);   // 8388608
  short* W2R    = (short*)(ws + 204472320);   // 2359296
  float* scores = (float*)(ws + 209059840);   // 1605632
  float* Msm    = (float*)(ws + 210665472);   // 1605632
  float* va     = (float*)(ws + 212271104);   // 2097152
  float* vb     = (float*)(ws + 214368256);   // 2097152
  unsigned int* maxM = (unsigned int*)(ws + 216465408);
  short* cm = xT;

  hipMemsetAsync(XcPad, 0, 84934656, stream);
  hipMemsetAsync(maxM, 0, 4, stream);

  k_cvt<<<16384, 256, 0, stream>>>(W1, W1b, 4194304);
  k_cvt<<<16384, 256, 0, stream>>>(W3, W3b, 4194304);
  k_w2r<<<4608, 256, 0, stream>>>(W2, W2R);
  k_xt<<<dim3(256, 32), 256, 0, stream>>>(x, xT);
  k_gemm1<<<1568, 512, 0, stream>>>(xT, W1b, g1, b1, XcPad);
  k_conv<<<3136, 512, 0, stream>>>(XcPad, W2R, g2, b2, ZcT);
  k_scores<<<256, 256, 0, stream>>>(ZcT, Wq, gq, bq, Wk, gk, bk, scores);
  k_softmax<<<1568, 256, 0, stream>>>(scores, Msm, maxM);
  k_tail<<<256, 256, 0, stream>>>(ZcT, Msm, Wout, gout, bout, Wcr, gcr, bcr,
                                  gcr1, bcr1, Wa, Wb, va, vb);
  k_cm<<<12544, 256, 0, stream>>>(ZcT, Msm, maxM, va, vb, ba, bb, cm);
  k_gemm2<<<1568, 512, 0, stream>>>(W3b, cm, g3, b3, x, out);
}

// Round 6
// 850.724 us; speedup vs baseline: 1.2518x; 1.0616x over previous
//
#include <hip/hip_runtime.h>
#include <hip/hip_bf16.h>
#include <stdint.h>

#define DI __device__ __forceinline__

typedef __attribute__((ext_vector_type(8))) short short8;
typedef __attribute__((ext_vector_type(4))) float floatx4;

DI float bf2f(short u) {
  union { unsigned int i; float f; } v;
  v.i = ((unsigned int)(unsigned short)u) << 16;
  return v.f;
}
DI short f2bf(float f) {
  union { float f; unsigned int i; } v; v.f = f;
  unsigned int r = v.i + 0x7FFFu + ((v.i >> 16) & 1u);
  return (short)(r >> 16);
}

DI void gload16(const void* g, void* l) {
  __builtin_amdgcn_global_load_lds(
      (const __attribute__((address_space(1))) void*)g,
      (__attribute__((address_space(3))) void*)l,
      16, 0, 0);
}

// ---------------- weight conversion ----------------
__global__ __launch_bounds__(256) void k_cvt(const float* __restrict__ src,
                                             short* __restrict__ dst, int n) {
  int i = blockIdx.x * 256 + threadIdx.x;
  if (i < n) dst[i] = f2bf(src[i]);
}

// W2 [c*64+po][pi][3][3] -> W2R [((c*9+tap)*64+po)*64+pi]
__global__ __launch_bounds__(256) void k_w2r(const float* __restrict__ W2,
                                             short* __restrict__ W2R) {
  int idx = blockIdx.x * 256 + threadIdx.x;
  if (idx >= 32 * 9 * 64 * 64) return;
  int pi = idx & 63;
  int po = (idx >> 6) & 63;
  int ct = idx >> 12;  // c*9+tap
  int tap = ct % 9, c = ct / 9;
  W2R[idx] = f2bf(W2[((c * 64 + po) * 64 + pi) * 9 + tap]);
}

// x [b][d][n] f32 -> xT [b*49+n][d] bf16
__global__ __launch_bounds__(256) void k_xt(const float* __restrict__ x,
                                            short* __restrict__ xT) {
  __shared__ float tile[64 * 49];
  int b = blockIdx.x, dc = blockIdx.y;
  const float* xp = x + ((size_t)b * 2048 + dc * 64) * 49;
  for (int i = threadIdx.x; i < 64 * 49; i += 256) tile[i] = xp[i];
  __syncthreads();
  for (int i = threadIdx.x; i < 64 * 49; i += 256) {
    int n = i >> 6, dl = i & 63;
    xT[((size_t)(b * 49 + n)) * 2048 + dc * 64 + dl] = f2bf(tile[dl * 49 + n]);
  }
}

// ---------------- GEMM1: XcPad[b][81][e] = BN(xT @ W1^T) ----------------
// 512 thr / 8 waves, BK=64, counted-vmcnt dbuf, XOR-swizzled LDS reads.
__global__ __launch_bounds__(512, 4) void k_gemm1(
    const short* __restrict__ xT, const short* __restrict__ W1b,
    const float* __restrict__ g1, const float* __restrict__ b1,
    short* __restrict__ XcPad) {
  __shared__ __attribute__((aligned(16))) short As[2][8192];
  __shared__ __attribute__((aligned(16))) short Bs[2][8192];
  const int tid = threadIdx.x;
  const int wave = tid >> 6, lane = tid & 63;
  const int wg = blockIdx.x;
  const int swz = (wg & 7) * 196 + (wg >> 3);
  const int mt = swz >> 4, et = swz & 15;
  // staging: row r8 (+64), chunk p0 of 8 x 16B per 64-elem row; source pre-swizzled
  const int r8 = tid >> 3, p0 = tid & 7;
  const int gsw = ((p0 ^ (r8 & 7)) << 3);
  const short* aR0 = xT + (size_t)(mt * 128 + r8) * 2048 + gsw;
  const short* aR1 = aR0 + (size_t)64 * 2048;
  const short* bR0 = W1b + (size_t)(et * 128 + r8) * 2048 + gsw;
  const short* bR1 = bR0 + (size_t)64 * 2048;
  const int lo0 = r8 * 64 + p0 * 8;
  const int lo1 = (r8 + 64) * 64 + p0 * 8;
  const int wr = wave >> 2, wc = wave & 3;  // 2(M) x 4(N) wave grid
  const int la = lane & 15, q = lane >> 4, l7 = lane & 7;
  const int cx0 = ((q) ^ l7) << 3;
  const int cx1 = ((4 + q) ^ l7) << 3;
  int arow[4], brow[2];
#pragma unroll
  for (int i = 0; i < 4; ++i) arow[i] = (wr * 64 + i * 16 + la) * 64;
#pragma unroll
  for (int j = 0; j < 2; ++j) brow[j] = (wc * 32 + j * 16 + la) * 64;
  floatx4 acc[4][2] = {};
  auto STAGE = [&](int buf, int kt) {
    const int ko = kt * 64;
    gload16(aR0 + ko, &As[buf][lo0]);
    gload16(aR1 + ko, &As[buf][lo1]);
    gload16(bR0 + ko, &Bs[buf][lo0]);
    gload16(bR1 + ko, &Bs[buf][lo1]);
  };
  auto COMPUTE = [&](int buf) {
#pragma unroll
    for (int kk = 0; kk < 2; ++kk) {
      const int cx = kk ? cx1 : cx0;
      short8 a[4], b[2];
#pragma unroll
      for (int i = 0; i < 4; ++i) a[i] = *(const short8*)&As[buf][arow[i] + cx];
#pragma unroll
      for (int j = 0; j < 2; ++j) b[j] = *(const short8*)&Bs[buf][brow[j] + cx];
#pragma unroll
      for (int i = 0; i < 4; ++i)
#pragma unroll
        for (int j = 0; j < 2; ++j)
          acc[i][j] = __builtin_amdgcn_mfma_f32_16x16x32_bf16(a[i], b[j], acc[i][j], 0, 0, 0);
    }
  };
  STAGE(0, 0);
  int cur = 0;
#pragma unroll 1
  for (int kt = 0; kt < 31; ++kt) {
    STAGE(cur ^ 1, kt + 1);
    asm volatile("s_waitcnt vmcnt(4)" ::: "memory");
    __builtin_amdgcn_s_barrier();
    COMPUTE(cur);
    __builtin_amdgcn_s_barrier();
    cur ^= 1;
  }
  asm volatile("s_waitcnt vmcnt(0)" ::: "memory");
  __builtin_amdgcn_s_barrier();
  COMPUTE(cur);
  const float rs = rsqrtf(1.0f + 1e-5f);
  size_t abase[16];
#pragma unroll
  for (int i = 0; i < 4; ++i)
#pragma unroll
    for (int r = 0; r < 4; ++r) {
      int m = mt * 128 + wr * 64 + i * 16 + (lane >> 4) * 4 + r;
      int bb = m / 49, n = m % 49, h = n / 7, w = n % 7;
      abase[i * 4 + r] = ((size_t)bb * 81 + (h + 1) * 9 + (w + 1)) * 2048;
    }
#pragma unroll
  for (int j = 0; j < 2; ++j) {
    int e = et * 128 + wc * 32 + j * 16 + (lane & 15);
    float s = g1[e] * rs, bo = b1[e];
#pragma unroll
    for (int i = 0; i < 4; ++i)
#pragma unroll
      for (int r = 0; r < 4; ++r)
        XcPad[abase[i * 4 + r] + e] = f2bf(acc[i][j][r] * s + bo);
  }
}

// ---------------- grouped 3x3 conv: 9 taps, BK=64/tap ----------------
// 512 thr / 8 waves, counted-vmcnt dbuf, XOR-swizzled LDS reads.
__global__ __launch_bounds__(512, 4) void k_conv(
    const short* __restrict__ XcPad, const short* __restrict__ W2R,
    const float* __restrict__ g2, const float* __restrict__ b2,
    short* __restrict__ ZcT) {
  __shared__ __attribute__((aligned(16))) short As[2][8192];
  __shared__ __attribute__((aligned(16))) short Ws[2][4096];
  const int tid = threadIdx.x;
  const int wave = tid >> 6, lane = tid & 63;
  const int wg = blockIdx.x;
  const int swz = (wg & 7) * 392 + (wg >> 3);
  const int mt = swz >> 5, c = swz & 31;
  const int r8 = tid >> 3, p0 = tid & 7;
  const int gsw = ((p0 ^ (r8 & 7)) << 3);
  // spatial rows r8 and r8+64 of this m-tile (center-tap bases in padded layout)
  int m0 = mt * 128 + r8;
  int b0 = m0 / 49, n0 = m0 % 49, h0 = n0 / 7, w0 = n0 % 7;
  int m1 = m0 + 64;
  int b1v = m1 / 49, n1 = m1 % 49, h1 = n1 / 7, w1 = n1 % 7;
  const short* aB0 = XcPad + ((size_t)b0 * 81 + (h0 + 1) * 9 + (w0 + 1)) * 2048 + c * 64 + gsw;
  const short* aB1 = XcPad + ((size_t)b1v * 81 + (h1 + 1) * 9 + (w1 + 1)) * 2048 + c * 64 + gsw;
  const short* wB = W2R + (size_t)c * 9 * 4096 + r8 * 64 + gsw;
  const int lo0 = r8 * 64 + p0 * 8;
  const int lo1 = (r8 + 64) * 64 + p0 * 8;
  const int wr = wave >> 1, wc = wave & 1;  // 4(M) x 2(N) wave grid
  const int la = lane & 15, q = lane >> 4, l7 = lane & 7;
  const int cx0 = ((q) ^ l7) << 3;
  const int cx1 = ((4 + q) ^ l7) << 3;
  int arow[2], brow[2];
#pragma unroll
  for (int i = 0; i < 2; ++i) arow[i] = (wr * 32 + i * 16 + la) * 64;
#pragma unroll
  for (int j = 0; j < 2; ++j) brow[j] = (wc * 32 + j * 16 + la) * 64;
  floatx4 acc[2][2] = {};
  auto STAGE = [&](int buf, int tap) {
    const int toff = ((tap / 3 - 1) * 9 + (tap % 3 - 1)) * 2048;
    gload16(aB0 + toff, &As[buf][lo0]);
    gload16(aB1 + toff, &As[buf][lo1]);
    gload16(wB + tap * 4096, &Ws[buf][lo0]);
  };
  auto COMPUTE = [&](int buf) {
#pragma unroll
    for (int kk = 0; kk < 2; ++kk) {
      const int cx = kk ? cx1 : cx0;
      short8 a[2], b[2];
#pragma unroll
      for (int i = 0; i < 2; ++i) a[i] = *(const short8*)&As[buf][arow[i] + cx];
#pragma unroll
      for (int j = 0; j < 2; ++j) b[j] = *(const short8*)&Ws[buf][brow[j] + cx];
#pragma unroll
      for (int i = 0; i < 2; ++i)
#pragma unroll
        for (int j = 0; j < 2; ++j)
          acc[i][j] = __builtin_amdgcn_mfma_f32_16x16x32_bf16(a[i], b[j], acc[i][j], 0, 0, 0);
    }
  };
  STAGE(0, 0);
  int cur = 0;
#pragma unroll 1
  for (int tap = 0; tap < 8; ++tap) {
    STAGE(cur ^ 1, tap + 1);
    asm volatile("s_waitcnt vmcnt(3)" ::: "memory");
    __builtin_amdgcn_s_barrier();
    COMPUTE(cur);
    __builtin_amdgcn_s_barrier();
    cur ^= 1;
  }
  asm volatile("s_waitcnt vmcnt(0)" ::: "memory");
  __builtin_amdgcn_s_barrier();
  COMPUTE(cur);
  const float rs = rsqrtf(1.0f + 1e-5f);
#pragma unroll
  for (int j = 0; j < 2; ++j) {
    int e = c * 64 + wc * 32 + j * 16 + (lane & 15);
    float s = g2[e] * rs, bo = b2[e];
#pragma unroll
    for (int i = 0; i < 2; ++i)
#pragma unroll
      for (int r = 0; r < 4; ++r) {
        int m = mt * 128 + wr * 32 + i * 16 + (lane >> 4) * 4 + r;
        ZcT[(size_t)m * 2048 + e] = f2bf(acc[i][j][r] * s + bo);
      }
  }
}

// ---------------- fused pooled-mean + q + scores ----------------
__global__ __launch_bounds__(256) void k_scores(
    const short* __restrict__ ZcT, const float* __restrict__ Wq,
    const float* __restrict__ gq, const float* __restrict__ bq,
    const float* __restrict__ Wk, const float* __restrict__ gk,
    const float* __restrict__ bk, float* __restrict__ scores) {
  int b = blockIdx.x, t = threadIdx.x;
  __shared__ float pooled[2048];
  __shared__ float qv[128];
  const float rs = rsqrtf(1.0f + 1e-5f);
  for (int e = t; e < 2048; e += 256) {
    float s = 0.f;
    for (int n = 0; n < 49; ++n) s += bf2f(ZcT[((size_t)(b * 49 + n)) * 2048 + e]);
    pooled[e] = s * (1.0f / 49.0f);
  }
  __syncthreads();
  if (t < 128) {
    int c = t >> 2;
    float s = 0.f;
    for (int pi = 0; pi < 64; ++pi) s += Wq[t * 64 + pi] * pooled[c * 64 + pi];
    qv[t] = s * gq[t] * rs + bq[t];
  }
  __syncthreads();
  for (int idx = t; idx < 1568; idx += 256) {
    int c = idx / 49, n = idx % 49;
    const short8* z = (const short8*)&ZcT[((size_t)(b * 49 + n)) * 2048 + c * 64];
    float acc[4] = {0.f, 0.f, 0.f, 0.f};
#pragma unroll
    for (int p8 = 0; p8 < 8; ++p8) {
      short8 v = z[p8];
#pragma unroll
      for (int j = 0; j < 8; ++j) {
        float zv = bf2f(v[j]);
#pragma unroll
        for (int pq = 0; pq < 4; ++pq)
          acc[pq] += Wk[(c * 4 + pq) * 64 + p8 * 8 + j] * zv;
      }
    }
    float sc = 0.f;
#pragma unroll
    for (int pq = 0; pq < 4; ++pq) {
      float kv = acc[pq] * gk[c * 4 + pq] * rs + bk[c * 4 + pq];
      sc += qv[c * 4 + pq] * kv;
    }
    scores[b * 1568 + idx] = sc;
  }
}

// ---------------- softmax over BATCH dim (torch Softmax2d quirk) ----------
__global__ __launch_bounds__(256) void k_softmax(const float* __restrict__ scores,
                                                 float* __restrict__ Msm,
                                                 unsigned int* __restrict__ maxM) {
  int cn = blockIdx.x, t = threadIdx.x;  // t = b
  float v = scores[t * 1568 + cn];
  __shared__ float red[4], red2[4];
  float m = v;
#pragma unroll
  for (int o = 1; o < 64; o <<= 1) m = fmaxf(m, __shfl_xor(m, o));
  if ((t & 63) == 0) red[t >> 6] = m;
  __syncthreads();
  m = fmaxf(fmaxf(red[0], red[1]), fmaxf(red[2], red[3]));
  float e = expf(v - m);
  float s = e;
#pragma unroll
  for (int o = 1; o < 64; o <<= 1) s += __shfl_xor(s, o);
  if ((t & 63) == 0) red2[t >> 6] = s;
  __syncthreads();
  s = red2[0] + red2[1] + red2[2] + red2[3];
  Msm[t * 1568 + cn] = e / s;
  if (t == 0) atomicMax(maxM, __float_as_uint(1.0f / s));  // column max of M == 1/sum
}

// ---------------- per-batch attention tail: zout->hc->A->hc_->va/vb -------
__global__ __launch_bounds__(256) void k_tail(
    const short* __restrict__ ZcT, const float* __restrict__ Msm,
    const float* __restrict__ Wout, const float* __restrict__ gout,
    const float* __restrict__ bout, const float* __restrict__ Wcr,
    const float* __restrict__ gcr, const float* __restrict__ bcr,
    const float* __restrict__ gcr1, const float* __restrict__ bcr1,
    const float* __restrict__ Wa, const float* __restrict__ Wb,
    float* __restrict__ va, float* __restrict__ vb) {
  int b = blockIdx.x, t = threadIdx.x;
  __shared__ float Mrow[1568];
  __shared__ float zout[2048];
  __shared__ float hcl[128];
  __shared__ float tb[1024];
  __shared__ float hcp[128];
  const float rs = rsqrtf(1.0f + 1e-5f);
  for (int i = t; i < 1568; i += 256) Mrow[i] = Msm[b * 1568 + i];
  __syncthreads();
  for (int e = t; e < 2048; e += 256) {
    int c = e >> 6;
    float s = 0.f;
    for (int n = 0; n < 49; ++n)
      s += bf2f(ZcT[((size_t)(b * 49 + n)) * 2048 + e]) * Mrow[c * 49 + n];
    zout[e] = s;
  }
  __syncthreads();
  if (t < 128) {
    int c = t >> 2;
    float s = 0.f;
    for (int p = 0; p < 64; ++p) s += Wout[t * 64 + p] * zout[c * 64 + p];
    hcl[t] = s * gout[t] * rs + bout[t];
  }
  __syncthreads();
  for (int i = t; i < 1024; i += 256) {
    int c = i >> 5;
    float s = 0.f;
#pragma unroll
    for (int k = 0; k < 4; ++k) s += Wcr[i * 4 + k] * hcl[c * 4 + k];
    tb[i] = tanhf(s * gcr[i] * rs + bcr[i]);
  }
  __syncthreads();
  if (t < 128) {
    int i = t >> 2, pq = t & 3;
    float s = hcl[t];
    for (int j = 0; j < 32; ++j) s += tb[j * 32 + i] * hcl[j * 4 + pq];
    hcp[t] = fmaxf(s * gcr1[t] * rs + bcr1[t], 0.0f);
  }
  __syncthreads();
  for (int e = t; e < 2048; e += 256) {
    int c = e >> 6;
    float sa = 0.f, sb = 0.f;
#pragma unroll
    for (int pq = 0; pq < 4; ++pq) {
      float h = hcp[c * 4 + pq];
      sa += Wa[e * 4 + pq] * h;
      sb += Wb[e * 4 + pq] * h;
    }
    va[b * 2048 + e] = sa;
    vb[b * 2048 + e] = sb;
  }
}

// ---------------- cm = Zc * relu(Zc*alpha + beta), vectorized ----------------
__global__ __launch_bounds__(256) void k_cm(
    const short* __restrict__ ZcT, const float* __restrict__ Msm,
    const unsigned int* __restrict__ maxM, const float* __restrict__ va,
    const float* __restrict__ vb, const float* __restrict__ ba,
    const float* __restrict__ bb, short* __restrict__ cm) {
  int m = blockIdx.x;
  int b = m / 49, n = m % 49;
  __shared__ float Minv[32];
  if (threadIdx.x < 32) {
    float mx = __uint_as_float(*maxM);
    Minv[threadIdx.x] = Msm[b * 1568 + threadIdx.x * 49 + n] / mx;
  }
  __syncthreads();
  const int e0 = threadIdx.x * 8;
  short8 z8 = *(const short8*)&ZcT[(size_t)m * 2048 + e0];
  const float mi = Minv[e0 >> 6];
  short8 o;
#pragma unroll
  for (int j = 0; j < 8; ++j) {
    float zc = bf2f(z8[j]);
    float al = va[b * 2048 + e0 + j] * mi + ba[e0 + j];
    float bt = vb[b * 2048 + e0 + j] * mi + bb[e0 + j];
    float xc = fmaxf(zc * al + bt, 0.0f);
    o[j] = f2bf(zc * xc);
  }
  *(short8*)&cm[(size_t)m * 2048 + e0] = o;
}

// ---------------- GEMM2: OUT[b][d][n] = BN(W3 @ cm^T) + x ----------------
// 512 thr / 8 waves, BK=64, counted-vmcnt dbuf, XOR-swizzled LDS reads.
__global__ __launch_bounds__(512, 4) void k_gemm2(
    const short* __restrict__ W3b, const short* __restrict__ cm,
    const float* __restrict__ g3, const float* __restrict__ b3,
    const float* __restrict__ x, float* __restrict__ out) {
  __shared__ __attribute__((aligned(16))) short As[2][8192];
  __shared__ __attribute__((aligned(16))) short Bs[2][8192];
  const int tid = threadIdx.x;
  const int wave = tid >> 6, lane = tid & 63;
  const int wg = blockIdx.x;
  const int swz = (wg & 7) * 196 + (wg >> 3);
  const int mt = swz >> 4, dt = swz & 15;
  const int r8 = tid >> 3, p0 = tid & 7;
  const int gsw = ((p0 ^ (r8 & 7)) << 3);
  const short* aR0 = W3b + (size_t)(dt * 128 + r8) * 2048 + gsw;
  const short* aR1 = aR0 + (size_t)64 * 2048;
  const short* bR0 = cm + (size_t)(mt * 128 + r8) * 2048 + gsw;
  const short* bR1 = bR0 + (size_t)64 * 2048;
  const int lo0 = r8 * 64 + p0 * 8;
  const int lo1 = (r8 + 64) * 64 + p0 * 8;
  const int wr = wave >> 2, wc = wave & 3;  // 2(d) x 4(m) wave grid
  const int la = lane & 15, q = lane >> 4, l7 = lane & 7;
  const int cx0 = ((q) ^ l7) << 3;
  const int cx1 = ((4 + q) ^ l7) << 3;
  int arow[4], brow[2];
#pragma unroll
  for (int i = 0; i < 4; ++i) arow[i] = (wr * 64 + i * 16 + la) * 64;
#pragma unroll
  for (int j = 0; j < 2; ++j) brow[j] = (wc * 32 + j * 16 + la) * 64;
  floatx4 acc[4][2] = {};
  auto STAGE = [&](int buf, int kt) {
    const int ko = kt * 64;
    gload16(aR0 + ko, &As[buf][lo0]);
    gload16(aR1 + ko, &As[buf][lo1]);
    gload16(bR0 + ko, &Bs[buf][lo0]);
    gload16(bR1 + ko, &Bs[buf][lo1]);
  };
  auto COMPUTE = [&](int buf) {
#pragma unroll
    for (int kk = 0; kk < 2; ++kk) {
      const int cx = kk ? cx1 : cx0;
      short8 a[4], b[2];
#pragma unroll
      for (int i = 0; i < 4; ++i) a[i] = *(const short8*)&As[buf][arow[i] + cx];
#pragma unroll
      for (int j = 0; j < 2; ++j) b[j] = *(const short8*)&Bs[buf][brow[j] + cx];
#pragma unroll
      for (int i = 0; i < 4; ++i)
#pragma unroll
        for (int j = 0; j < 2; ++j)
          acc[i][j] = __builtin_amdgcn_mfma_f32_16x16x32_bf16(a[i], b[j], acc[i][j], 0, 0, 0);
    }
  };
  STAGE(0, 0);
  int cur = 0;
#pragma unroll 1
  for (int kt = 0; kt < 31; ++kt) {
    STAGE(cur ^ 1, kt + 1);
    asm volatile("s_waitcnt vmcnt(4)" ::: "memory");
    __builtin_amdgcn_s_barrier();
    COMPUTE(cur);
    __builtin_amdgcn_s_barrier();
    cur ^= 1;
  }
  asm volatile("s_waitcnt vmcnt(0)" ::: "memory");
  __builtin_amdgcn_s_barrier();
  COMPUTE(cur);
  const float rs = rsqrtf(1.0f + 1e-5f);
  size_t cbb[2];
#pragma unroll
  for (int j = 0; j < 2; ++j) {
    int m = mt * 128 + wc * 32 + j * 16 + (lane & 15);
    int bb = m / 49, n = m % 49;
    cbb[j] = (size_t)bb * (2048 * 49) + n;
  }
#pragma unroll
  for (int i = 0; i < 4; ++i)
#pragma unroll
    for (int r = 0; r < 4; ++r) {
      int d = dt * 128 + wr * 64 + i * 16 + (lane >> 4) * 4 + r;
      float s = g3[d] * rs, bo = b3[d];
      size_t dterm = (size_t)d * 49;
#pragma unroll
      for (int j = 0; j < 2; ++j) {
        size_t adr = cbb[j] + dterm;
        out[adr] = acc[i][j][r] * s + bo + x[adr];
      }
    }
}

// ---------------- launch ----------------
extern "C" void kernel_launch(void* const* d_in, const int* in_sizes, int n_in,
                              void* d_out, int out_size, void* d_ws, size_t ws_size,
                              hipStream_t stream) {
  (void)in_sizes; (void)n_in; (void)out_size; (void)ws_size;
  const float* x    = (const float*)d_in[0];
  const float* W1   = (const float*)d_in[1];
  const float* g1   = (const float*)d_in[2];
  const float* b1   = (const float*)d_in[3];
  const float* W2   = (const float*)d_in[4];
  const float* g2   = (const float*)d_in[5];
  const float* b2   = (const float*)d_in[6];
  const float* Wq   = (const float*)d_in[7];
  const float* gq   = (const float*)d_in[8];
  const float* bq   = (const float*)d_in[9];
  const float* Wk   = (const float*)d_in[10];
  const float* gk   = (const float*)d_in[11];
  const float* bk   = (const float*)d_in[12];
  const float* Wout = (const float*)d_in[13];
  const float* gout = (const float*)d_in[14];
  const float* bout = (const float*)d_in[15];
  const float* Wcr  = (const float*)d_in[16];
  const float* gcr  = (const float*)d_in[17];
  const float* bcr  = (const float*)d_in[18];
  const float* gcr1 = (const float*)d_in[19];
  const float* bcr1 = (const float*)d_in[20];
  const float* Wa   = (const float*)d_in[21];
  const float* ba   = (const float*)d_in[22];
  const float* Wb   = (const float*)d_in[23];
  const float* bb   = (const float*)d_in[24];
  const float* W3   = (const float*)d_in[25];
  const float* g3   = (const float*)d_in[26];
  const float* b3   = (const float*)d_in[27];
  float* out = (float*)d_out;

  char* ws = (char*)d_ws;
  short* XcPad  = (short*)(ws + 0);           // 256*81*2048*2 = 84934656
  short* xT     = (short*)(ws + 84934656);    // 12544*2048*2 = 51380224 (reused as cm)
  short* ZcT    = (short*)(ws + 136314880);   // 51380224
  short* W1b    = (short*)(ws + 187695104);   // 8388608
  short* W3b    = (short*)(ws + 196083712);   // 8388608
  short* W2R    = (short*)(ws + 204472320);   // 2359296
  float* scores = (float*)(ws + 209059840);   // 1605632
  float* Msm    = (float*)(ws + 210665472);   // 1605632
  float* va     = (float*)(ws + 212271104);   // 2097152
  float* vb     = (float*)(ws + 214368256);   // 2097152
  unsigned int* maxM = (unsigned int*)(ws + 216465408);
  short* cm = xT;

  hipMemsetAsync(XcPad, 0, 84934656, stream);
  hipMemsetAsync(maxM, 0, 4, stream);

  k_cvt<<<16384, 256, 0, stream>>>(W1, W1b, 4194304);
  k_cvt<<<16384, 256, 0, stream>>>(W3, W3b, 4194304);
  k_w2r<<<4608, 256, 0, stream>>>(W2, W2R);
  k_xt<<<dim3(256, 32), 256, 0, stream>>>(x, xT);
  k_gemm1<<<1568, 512, 0, stream>>>(xT, W1b, g1, b1, XcPad);
  k_conv<<<3136, 512, 0, stream>>>(XcPad, W2R, g2, b2, ZcT);
  k_scores<<<256, 256, 0, stream>>>(ZcT, Wq, gq, bq, Wk, gk, bk, scores);
  k_softmax<<<1568, 256, 0, stream>>>(scores, Msm, maxM);
  k_tail<<<256, 256, 0, stream>>>(ZcT, Msm, Wout, gout, bout, Wcr, gcr, bcr,
                                  gcr1, bcr1, Wa, Wb, va, vb);
  k_cm<<<12544, 256, 0, stream>>>(ZcT, Msm, maxM, va, vb, ba, bb, cm);
  k_gemm2<<<1568, 512, 0, stream>>>(W3b, cm, g3, b3, x, out);
}